// Round 8
// baseline (233.873 us; speedup 1.0000x reference)
//
#include <hip/hip_runtime.h>
#include <type_traits>
#include <utility>

#define B_ 2
#define S_ 2048
#define D_ 1024
#define H_ 16
#define HD_ 64
#define KDIM 1024

typedef __attribute__((ext_vector_type(8))) short    s16x8;
typedef __attribute__((ext_vector_type(8))) _Float16 h16x8;
typedef __attribute__((ext_vector_type(4))) float    f32x4;
typedef __attribute__((ext_vector_type(16))) float   f32x16;
typedef __attribute__((ext_vector_type(4))) int      i32x4;
typedef __attribute__((ext_vector_type(2))) int      i32x2;

// --- MFMA operand-type hedge (fp16) ---
template <typename T, typename = void> struct mfma_takes : std::false_type {};
template <typename T>
struct mfma_takes<T, std::void_t<decltype(__builtin_amdgcn_mfma_f32_16x16x32_f16(
    std::declval<T>(), std::declval<T>(), std::declval<f32x4>(), 0, 0, 0))>>
    : std::true_type {};
using frag8 = std::conditional_t<mfma_takes<h16x8>::value, h16x8, s16x8>;

__device__ __forceinline__ f32x4 mfma_f16(frag8 a, frag8 b, f32x4 c) {
  return __builtin_amdgcn_mfma_f32_16x16x32_f16(a, b, c, 0, 0, 0);
}
__device__ __forceinline__ f32x16 mfma32(frag8 a, frag8 b, f32x16 c) {
  return __builtin_amdgcn_mfma_f32_32x32x16_f16(a, b, c, 0, 0, 0);
}

__device__ __forceinline__ short f2h(float f) {  // RTNE f32 -> fp16 bits
  _Float16 h = (_Float16)f;
  short s; __builtin_memcpy(&s, &h, 2);
  return s;
}
__device__ __forceinline__ int pk2h(float a, float b) {  // v_cvt_pkrtz 2xfp16
  auto p = __builtin_amdgcn_cvt_pkrtz(a, b);   // __fp16 ext_vector(2)
  int r; __builtin_memcpy(&r, &p, 4); return r;
}
__device__ __forceinline__ frag8 ld_frag(const short* p) {
  return __builtin_bit_cast(frag8, *(const i32x4*)p);
}
__device__ __forceinline__ float fast_exp2(float x) {
  return __builtin_amdgcn_exp2f(x);
}
// v_permlane32_swap_b32: vdst[32:63] <-> src0[0:31] (both operands modified)
__device__ __forceinline__ void pl32swap(int& a, int& b) {
  asm volatile("v_permlane32_swap_b32 %0, %1" : "+v"(a), "+v"(b));
}

typedef __attribute__((address_space(1))) const void gvoid;
typedef __attribute__((address_space(3))) void lvoid;
__device__ __forceinline__ void async_copy16(const void* g, void* l) {
  __builtin_amdgcn_global_load_lds((gvoid*)g, (lvoid*)l, 16, 0, 0);
}

#define RAW_BARRIER() asm volatile("s_barrier" ::: "memory")
#define WAITCNT_VM(n) asm volatile("s_waitcnt vmcnt(" #n ")" ::: "memory")

// ---------------------------------------------------------------------------
// R8: weights-only fp32 -> fp16 convert (q/k/v conversion fused into
// gemm_qkv A-staging — conv_all's 100MB pass shrinks to 25MB).
// 2048 blocks x 256 thr, 8 elems/thread.
// ---------------------------------------------------------------------------
__global__ __launch_bounds__(256)
void conv_w(const float* __restrict__ Wq, const float* __restrict__ Wk,
            const float* __restrict__ Wv, const float* __restrict__ Wo,
            short* __restrict__ wq, short* __restrict__ wk,
            short* __restrict__ wv, short* __restrict__ wo) {
  const int blk = blockIdx.x;
  const float* src; short* dst; int base;
  if (blk < 512)        { src = Wq; dst = wq; base = blk; }
  else if (blk < 1024)  { src = Wk; dst = wk; base = blk - 512; }
  else if (blk < 1536)  { src = Wv; dst = wv; base = blk - 1024; }
  else                  { src = Wo; dst = wo; base = blk - 1536; }
  const int i = base * 2048 + threadIdx.x * 8;
  float4 a0 = *(const float4*)(src + i);
  float4 a1 = *(const float4*)(src + i + 4);
  short h[8] = { f2h(a0.x), f2h(a0.y), f2h(a0.z), f2h(a0.w),
                 f2h(a1.x), f2h(a1.y), f2h(a1.z), f2h(a1.w) };
  i32x4 ph; __builtin_memcpy(&ph, h, 16);
  *(i32x4*)(dst + i) = ph;
}

// ---------------------------------------------------------------------------
// QKV projection GEMM. R8: A operand read DIRECTLY from fp32 q/k/v inputs,
// reg-staged (T14 split: loads issued one iter ahead; f2h RTNE — bit-
// identical to old conv_all path; ds_write_b128 into the SAME XOR-swizzled
// layout so frag reads are untouched). B (weights) stays global_load_lds
// from conv_w's fp16. vmcnt protocol: per-iter issue order [4 A-loads,
// 2 B-asyncs]; steady vmcnt(2) drains A(kk+32)+B(kk), leaves B(kk+32).
// A-slot (buf+1)%3 write is race-free: its last reader finished >=2
// barriers earlier (two-barrier ring). Tile 128x128, BK=32, triple ring.
// A-GROUPED XCD DECODE unchanged. Epilogue full-line b128 stores.
// ---------------------------------------------------------------------------
__global__ __launch_bounds__(256, 3)
void gemm_qkv(const float* __restrict__ Aq, const float* __restrict__ Ak,
              const float* __restrict__ Av, const short* __restrict__ wq,
              const short* __restrict__ wk, const short* __restrict__ wv,
              const float* __restrict__ bq, const float* __restrict__ bk,
              const float* __restrict__ bv, short* __restrict__ Qf,
              short* __restrict__ Kf, short* __restrict__ Vt, float QS) {
  __shared__ short As[3 * 4096];
  __shared__ short Bs[3 * 4096];

  const int blk = blockIdx.x;
  const int xcd = blk & 7, i = blk >> 3;      // i in [0,96)
  const int p = (i >> 3) * 8 + xcd;           // A-tile id, p ≡ xcd (mod 8)
  const int bn = i & 7;
  const int z = p >> 5, bm = p & 31;
  const float* Af = z == 0 ? Aq : z == 1 ? Ak : Av;
  const short* Wp = z == 0 ? wq : z == 1 ? wk : wv;
  const float* bias = z == 0 ? bq : z == 1 ? bk : bv;
  short* Out = z == 0 ? Qf : z == 1 ? Kf : Vt;
  const float scale = z == 0 ? QS : 1.0f;
  const int omode = z == 2 ? 2 : 1;

  const int t = threadIdx.x, wave = t >> 6, lane = t & 63;
  const int laneN = lane & 15, quad = lane >> 4;
  const int wm = wave & 1, wn = wave >> 1;

  f32x4 acc[4][4];
#pragma unroll
  for (int i2 = 0; i2 < 4; ++i2)
#pragma unroll
    for (int j = 0; j < 4; ++j)
#pragma unroll
      for (int r = 0; r < 4; ++r) acc[i2][j][r] = 0.f;

  // ---- A reg-stage descriptors: 2 chunks/thread, same swizzled layout ----
  const int ch0 = t, ch1 = 256 + t;
  const int ar0 = ch0 >> 2, ag0 = (ch0 & 3) ^ ((ar0 >> 1) & 3);
  const int ar1 = ch1 >> 2, ag1 = (ch1 & 3) ^ ((ar1 >> 1) & 3);
  const float* ap0 = Af + (size_t)(bm * 128 + ar0) * KDIM + ag0 * 8;
  const float* ap1 = Af + (size_t)(bm * 128 + ar1) * KDIM + ag1 * 8;

  f32x4 rA0a, rA0b, rA1a, rA1b;   // pending A tile (fp32)

  auto loadA = [&](int kk) {
    rA0a = *(const f32x4*)(ap0 + kk);
    rA0b = *(const f32x4*)(ap0 + kk + 4);
    rA1a = *(const f32x4*)(ap1 + kk);
    rA1b = *(const f32x4*)(ap1 + kk + 4);
  };
  auto writeA = [&](int slot) {
    short pk[8];
    pk[0] = f2h(rA0a[0]); pk[1] = f2h(rA0a[1]);
    pk[2] = f2h(rA0a[2]); pk[3] = f2h(rA0a[3]);
    pk[4] = f2h(rA0b[0]); pk[5] = f2h(rA0b[1]);
    pk[6] = f2h(rA0b[2]); pk[7] = f2h(rA0b[3]);
    i32x4 w0; __builtin_memcpy(&w0, pk, 16);
    *(i32x4*)(As + slot * 4096 + ch0 * 8) = w0;
    pk[0] = f2h(rA1a[0]); pk[1] = f2h(rA1a[1]);
    pk[2] = f2h(rA1a[2]); pk[3] = f2h(rA1a[3]);
    pk[4] = f2h(rA1b[0]); pk[5] = f2h(rA1b[1]);
    pk[6] = f2h(rA1b[2]); pk[7] = f2h(rA1b[3]);
    i32x4 w1; __builtin_memcpy(&w1, pk, 16);
    *(i32x4*)(As + slot * 4096 + ch1 * 8) = w1;
  };
  auto stageB = [&](int slot, int kk) {   // 2 asyncs/thread
#pragma unroll
    for (int j = 0; j < 2; ++j) {
      const int chunk = j * 256 + t;
      const int row = chunk >> 2;
      const int gg = (chunk & 3) ^ ((row >> 1) & 3);
      async_copy16(Wp + (size_t)(bn * 128 + row) * KDIM + kk + gg * 8,
                   Bs + slot * 4096 + chunk * 8);
    }
  };

  // prologue: A(0) -> LDS slot0; A(32) in regs; B(0),B(32) async
  loadA(0);
  writeA(0);          // compiler inserts the vm-wait for the loads
  loadA(32);
  stageB(0, 0);
  stageB(1, 32);

  int buf = 0;
  for (int kk = 0; kk < KDIM; kk += 32) {
    if (kk + 64 < KDIM) {
      WAITCNT_VM(2);        // drain A(kk+32) loads + B(kk); leave B(kk+32)
      int ns = buf + 1; if (ns >= 3) ns -= 3;
      writeA(ns);           // A(kk+32) -> LDS for next iter
      loadA(kk + 64);
      int nb = buf + 2; if (nb >= 3) nb -= 3;
      stageB(nb, kk + 64);
    } else if (kk + 32 < KDIM) {
      WAITCNT_VM(2);
      int ns = buf + 1; if (ns >= 3) ns -= 3;
      writeA(ns);
    } else {
      WAITCNT_VM(0);
    }
    RAW_BARRIER();

    frag8 aF[4], bF[4];
#pragma unroll
    for (int mi = 0; mi < 4; ++mi) {
      const int row = wm * 64 + mi * 16 + laneN;
      aF[mi] = ld_frag(As + buf * 4096 + row * 32 +
                       ((quad ^ ((row >> 1) & 3)) * 8));
    }
#pragma unroll
    for (int ni = 0; ni < 4; ++ni) {
      const int row = wn * 64 + ni * 16 + laneN;
      bF[ni] = ld_frag(Bs + buf * 4096 + row * 32 +
                       ((quad ^ ((row >> 1) & 3)) * 8));
    }
#pragma unroll
    for (int mi = 0; mi < 4; ++mi)
#pragma unroll
      for (int ni = 0; ni < 4; ++ni)
        acc[mi][ni] = mfma_f16(aF[mi], bF[ni], acc[mi][ni]);
    RAW_BARRIER();
    buf = buf + 1 == 3 ? 0 : buf + 1;
  }

  // ---- Epilogue via per-wave LDS restage (As free past final barrier).
  short* scr = As + wave * 1152;
  const int h = bn * 2 + wn;
  if (omode == 2) {
    const int bidx = bm >> 4;
    const int sbase = (bm * 128 + wm * 64) & 2047;
#pragma unroll
    for (int ni = 0; ni < 4; ++ni) {
      const float bb = bias[bn * 128 + wn * 64 + ni * 16 + laneN];
#pragma unroll
      for (int mi = 0; mi < 4; ++mi) {
        short pk[4];
#pragma unroll
        for (int r = 0; r < 4; ++r) pk[r] = f2h(acc[mi][ni][r] + bb);
        i32x2 w; __builtin_memcpy(&w, pk, 8);
        *(i32x2*)(scr + laneN * 72 + mi * 16 + quad * 4) = w;
      }
#pragma unroll
      for (int j = 0; j < 2; ++j) {
        const int ff = lane * 2 + j, hdr = ff >> 3, ch = ff & 7;
        i32x4 v = *(const i32x4*)(scr + hdr * 72 + ch * 8);
        *(i32x4*)(Vt + (((size_t)(bidx * H_ + h)) * HD_ + ni * 16 + hdr) * S_ +
                  sbase + ch * 8) = v;
      }
    }
  } else {
#pragma unroll
    for (int mi = 0; mi < 4; ++mi) {
#pragma unroll
      for (int ni = 0; ni < 4; ++ni) {
        const float bb = bias[bn * 128 + wn * 64 + ni * 16 + laneN];
#pragma unroll
        for (int r = 0; r < 4; ++r)
          scr[(quad * 4 + r) * 72 + ni * 16 + laneN] =
              f2h((acc[mi][ni][r] + bb) * scale);
      }
#pragma unroll
      for (int j = 0; j < 2; ++j) {
        const int ff = lane * 2 + j, row = ff >> 3, ch = ff & 7;
        const int rowg = bm * 128 + wm * 64 + mi * 16 + row;
        const int bidx = rowg >> 11, s = rowg & 2047;
        i32x4 v = *(const i32x4*)(scr + row * 72 + ch * 8);
        *(i32x4*)(Out + (((size_t)(bidx * H_ + h)) * S_ + s) * HD_ + ch * 8) = v;
      }
    }
  }
}

// ---------------------------------------------------------------------------
// O projection: fp16 A x fp16 Wo -> fp32. Tile 128(M)x64(N). BK=64
// double-buffered (48KB LDS), counted vm(6), 16 MFMA per barrier-pair.
// ---------------------------------------------------------------------------
__global__ __launch_bounds__(256, 3)
void gemm_out(const short* __restrict__ Ap, const short* __restrict__ Wp,
              const float* __restrict__ bias, float* __restrict__ Out) {
  __shared__ short As[2 * 8192];   // 2 x 128r x 64k
  __shared__ short Bs[2 * 4096];   // 2 x  64r x 64k
  const int blk = blockIdx.x;
  const int xcd = blk & 7, i = blk >> 3;      // i in [0,64)
  const int bm = (i >> 4) * 8 + xcd;          // bm ≡ xcd (mod 8)
  const int bn = i & 15;

  const int t = threadIdx.x, wave = t >> 6, lane = t & 63;
  const int laneN = lane & 15, quad = lane >> 4;
  const int wm = wave & 1, wn = wave >> 1;

  f32x4 acc[4][2];
#pragma unroll
  for (int i2 = 0; i2 < 4; ++i2)
#pragma unroll
    for (int j = 0; j < 2; ++j)
#pragma unroll
      for (int r = 0; r < 4; ++r) acc[i2][j][r] = 0.f;

  auto stage = [&](int buf, int kk) {   // 6 asyncs/thread per call
#pragma unroll
    for (int j = 0; j < 4; ++j) {       // A: 1024 chunks
      const int c = j * 256 + t;
      const int row = c >> 3, g = (c & 7) ^ (row & 7);
      async_copy16(Ap + (size_t)(bm * 128 + row) * KDIM + kk + g * 8,
                   As + buf * 8192 + c * 8);
    }
#pragma unroll
    for (int j = 0; j < 2; ++j) {       // B: 512 chunks
      const int c = j * 256 + t;
      const int row = c >> 3, g = (c & 7) ^ (row & 7);
      async_copy16(Wp + (size_t)(bn * 64 + row) * KDIM + kk + g * 8,
                   Bs + buf * 4096 + c * 8);
    }
  };

  // frag offsets: row*64 + ((quad+4*ks) ^ (row&7))*8
  int offA[4][2], offB[2][2];
#pragma unroll
  for (int mi = 0; mi < 4; ++mi) {
    const int row = wm * 64 + mi * 16 + laneN;
#pragma unroll
    for (int ks = 0; ks < 2; ++ks)
      offA[mi][ks] = row * 64 + (((quad + 4 * ks) ^ (row & 7)) * 8);
  }
#pragma unroll
  for (int ni = 0; ni < 2; ++ni) {
    const int row = wn * 32 + ni * 16 + laneN;
#pragma unroll
    for (int ks = 0; ks < 2; ++ks)
      offB[ni][ks] = row * 64 + (((quad + 4 * ks) ^ (row & 7)) * 8);
  }

  stage(0, 0);
  int buf = 0;
  for (int kk = 0; kk < KDIM; kk += 64) {
    if (kk + 64 < KDIM) {
      stage(buf ^ 1, kk + 64);
      WAITCNT_VM(6);        // current tile's 6 complete; next's in flight
    } else {
      WAITCNT_VM(0);
    }
    RAW_BARRIER();

    frag8 aF[4][2], bF[2][2];
#pragma unroll
    for (int mi = 0; mi < 4; ++mi) {
      aF[mi][0] = ld_frag(As + buf * 8192 + offA[mi][0]);
      aF[mi][1] = ld_frag(As + buf * 8192 + offA[mi][1]);
    }
#pragma unroll
    for (int ni = 0; ni < 2; ++ni) {
      bF[ni][0] = ld_frag(Bs + buf * 4096 + offB[ni][0]);
      bF[ni][1] = ld_frag(Bs + buf * 4096 + offB[ni][1]);
    }
#pragma unroll
    for (int mi = 0; mi < 4; ++mi)
#pragma unroll
      for (int ni = 0; ni < 2; ++ni) {
        acc[mi][ni] = mfma_f16(aF[mi][0], bF[ni][0], acc[mi][ni]);
        acc[mi][ni] = mfma_f16(aF[mi][1], bF[ni][1], acc[mi][ni]);
      }
    RAW_BARRIER();
    buf ^= 1;
  }

  // ---- Epilogue via per-wave LDS restage: [16 rows][36 f32] strip.
  float* scr = (float*)As + wave * 576;
#pragma unroll
  for (int mi = 0; mi < 4; ++mi) {
#pragma unroll
    for (int ni = 0; ni < 2; ++ni) {
      const float bb = bias[bn * 64 + wn * 32 + ni * 16 + laneN];
#pragma unroll
      for (int r = 0; r < 4; ++r)
        scr[(quad * 4 + r) * 36 + ni * 16 + laneN] = acc[mi][ni][r] + bb;
    }
#pragma unroll
    for (int j = 0; j < 2; ++j) {
      const int ff = lane * 2 + j, row = ff >> 3, ch = ff & 7;
      const int rowg = bm * 128 + wm * 64 + mi * 16 + row;
      f32x4 v = *(const f32x4*)(scr + row * 36 + ch * 4);
      *(f32x4*)(Out + (size_t)rowg * 1024 + bn * 64 + wn * 32 + ch * 4) = v;
    }
  }
}

// ---------------------------------------------------------------------------
// Flash attention, fp16. R7 structure (kept): 32 q/wave via 32x32x16 MFMA,
// in-register P (cvt_pkrtz + permlane32_swap), 512 blocks x 256 threads,
// ring-4 K/V 64KB, one barrier/kt, counted vm(8). 59.7us measured.
// ---------------------------------------------------------------------------
__global__ __launch_bounds__(256, 2)
void attn(const short* __restrict__ Qf, const short* __restrict__ Kf,
          const short* __restrict__ Vt_, short* __restrict__ Ow) {
  __shared__ short Ks[4 * 4096];     // 4 x 64k x 64d
  __shared__ short Vts[4 * 4096];    // 4 x 64d x 64k

  // XCD-locality: 512 blocks, 8 groups x 4 (h,b) pairs x 16 q-tiles of 128
  const int blk = blockIdx.x;
  const int xcd = blk & 7, local = blk >> 3;
  const int pair = xcd * 4 + (local >> 4);
  const int h = pair & 15, b = pair >> 4, qt = local & 15;
  const size_t head = ((size_t)b * H_ + h) * (size_t)S_ * HD_;

  const int t = threadIdx.x;
  const int wave = t >> 6, lane = t & 63;
  const int l31 = lane & 31, hi = lane >> 5;

  const int q0 = qt * 128 + wave * 32;

  // Q frags (B-operand of 32x32x16): col q = l31, contraction d = ds*16+hi*8
  frag8 qf[4];
  {
    const short* qp = Qf + head + (size_t)(q0 + l31) * HD_ + hi * 8;
#pragma unroll
    for (int ds = 0; ds < 4; ++ds) qf[ds] = ld_frag(qp + ds * 16);
  }

  // O^T accumulators: dt in {0,1}; C/D: col q = l31,
  // row d = dt*32 + (r&3) + 8*(r>>2) + 4*hi
  f32x16 o0, o1;
#pragma unroll
  for (int r = 0; r < 16; ++r) { o0[r] = 0.f; o1[r] = 0.f; }
  float m_r = -1e30f, l_r = 0.f;

  // ---- staging: 2 K-chunks + 2 V-chunks per thread (8KB tiles) ----
  const int c0 = t, c1 = 256 + t;
  const int r0 = c0 >> 3, gg0 = (c0 & 7) ^ (r0 & 7);
  const int r1 = c1 >> 3, gg1 = (c1 & 7) ^ (r1 & 7);
  const short* kp0 = Kf + head + (size_t)r0 * HD_ + gg0 * 8;  // += 4096/kt
  const short* kp1 = Kf + head + (size_t)r1 * HD_ + gg1 * 8;
  const short* vp0 = Vt_ + head + (size_t)r0 * S_ + gg0 * 8;  // += 64/kt
  const short* vp1 = Vt_ + head + (size_t)r1 * S_ + gg1 * 8;
  const int d0 = c0 * 8, d1 = c1 * 8;

  // frag offsets (same table serves K rows k and V rows d):
  // row = hf*32 + l31, granule = (j*2 + hi) ^ (row&7)
  int off2[2][4];
#pragma unroll
  for (int hf = 0; hf < 2; ++hf) {
    const int row = hf * 32 + l31;
#pragma unroll
    for (int j = 0; j < 4; ++j)
      off2[hf][j] = row * 64 + (((j * 2 + hi) ^ (row & 7)) * 8);
  }

  // prologue: stage tiles 0,1 (prefetch distance 2)
  async_copy16(kp0, Ks + d0);  async_copy16(kp1, Ks + d1);
  async_copy16(vp0, Vts + d0); async_copy16(vp1, Vts + d1);
  kp0 += 4096; kp1 += 4096; vp0 += 64; vp1 += 64;
  async_copy16(kp0, Ks + 4096 + d0);  async_copy16(kp1, Ks + 4096 + d1);
  async_copy16(vp0, Vts + 4096 + d0); async_copy16(vp1, Vts + 4096 + d1);
  kp0 += 4096; kp1 += 4096; vp0 += 64; vp1 += 64;

// One kt step. B0 = kt&3 compile-time; stage -> (B0+2)&3.
// STG: 1 = stage + vm(8); 2 = vm(4); 0 = vm(0).
#define ATTN_TILE(B0, STG)                                                   \
  {                                                                          \
    if (STG == 1) {                                                          \
      const int nb = ((B0) + 2) & 3;                                         \
      async_copy16(kp0, Ks + nb * 4096 + d0);                                \
      async_copy16(kp1, Ks + nb * 4096 + d1);                                \
      async_copy16(vp0, Vts + nb * 4096 + d0);                               \
      async_copy16(vp1, Vts + nb * 4096 + d1);                               \
      kp0 += 4096; kp1 += 4096; vp0 += 64; vp1 += 64;                        \
      WAITCNT_VM(8);                                                         \
    } else if (STG == 2) {                                                   \
      WAITCNT_VM(4);                                                         \
    } else {                                                                 \
      WAITCNT_VM(0);                                                         \
    }                                                                        \
    RAW_BARRIER();                                                           \
    const short* KbS = Ks + (B0) * 4096;                                     \
    const short* VbS = Vts + (B0) * 4096;                                    \
    /* S^T = K.Q^T: kh halves -> sA (k 0..31), sB (k 32..63) */              \
    f32x16 sA, sB;                                                           \
    _Pragma("unroll")                                                        \
    for (int r = 0; r < 16; ++r) { sA[r] = 0.f; sB[r] = 0.f; }               \
    __builtin_amdgcn_s_setprio(1);                                           \
    _Pragma("unroll")                                                        \
    for (int ds = 0; ds < 4; ++ds) {                                         \
      frag8 ka = ld_frag(KbS + off2[0][ds]);                                 \
      frag8 kb = ld_frag(KbS + off2[1][ds]);                                 \
      sA = mfma32(ka, qf[ds], sA);                                           \
      sB = mfma32(kb, qf[ds], sB);                                           \
    }                                                                        \
    __builtin_amdgcn_s_setprio(0);                                           \
    /* online softmax: 31 in-lane + 1 shfl32; defer-max THR=8 */             \
    {                                                                        \
      float mA = sA[0], mB = sB[0];                                          \
      _Pragma("unroll")                                                      \
      for (int r = 1; r < 16; ++r) {                                         \
        mA = fmaxf(mA, sA[r]); mB = fmaxf(mB, sB[r]);                        \
      }                                                                      \
      float mx = fmaxf(mA, mB);                                              \
      mx = fmaxf(mx, __shfl_xor(mx, 32));                                    \
      if (__any(mx > m_r + 8.f)) {                                           \
        const float mn = fmaxf(m_r, mx);                                     \
        const float al = fast_exp2(m_r - mn);                                \
        m_r = mn; l_r *= al;                                                 \
        _Pragma("unroll")                                                    \
        for (int r = 0; r < 16; ++r) { o0[r] *= al; o1[r] *= al; }           \
      }                                                                      \
      float rs = 0.f;                                                        \
      _Pragma("unroll")                                                      \
      for (int r = 0; r < 16; ++r) {                                         \
        const float pa = fast_exp2(sA[r] - m_r);                             \
        const float pb = fast_exp2(sB[r] - m_r);                             \
        sA[r] = pa; sB[r] = pb; rs += pa + pb;                               \
      }                                                                      \
      rs += __shfl_xor(rs, 32);                                              \
      l_r += rs;                                                             \
    }                                                                        \
    /* P -> B-frags in registers: per k16-slice 4 cvt_pk + 2 permlane32 */   \
    frag8 pf0, pf1, pf2, pf3;                                                \
    {                                                                        \
      int w0, w1, w2, w3; i32x4 fw;                                          \
      w0 = pk2h(sA[0], sA[1]);   w1 = pk2h(sA[2], sA[3]);                    \
      w2 = pk2h(sA[4], sA[5]);   w3 = pk2h(sA[6], sA[7]);                    \
      pl32swap(w0, w2); pl32swap(w1, w3);                                    \
      fw[0] = w0; fw[1] = w1; fw[2] = w2; fw[3] = w3;                        \
      pf0 = __builtin_bit_cast(frag8, fw);                                   \
      w0 = pk2h(sA[8], sA[9]);   w1 = pk2h(sA[10], sA[11]);                  \
      w2 = pk2h(sA[12], sA[13]); w3 = pk2h(sA[14], sA[15]);                  \
      pl32swap(w0, w2); pl32swap(w1, w3);                                    \
      fw[0] = w0; fw[1] = w1; fw[2] = w2; fw[3] = w3;                        \
      pf1 = __builtin_bit_cast(frag8, fw);                                   \
      w0 = pk2h(sB[0], sB[1]);   w1 = pk2h(sB[2], sB[3]);                    \
      w2 = pk2h(sB[4], sB[5]);   w3 = pk2h(sB[6], sB[7]);                    \
      pl32swap(w0, w2); pl32swap(w1, w3);                                    \
      fw[0] = w0; fw[1] = w1; fw[2] = w2; fw[3] = w3;                        \
      pf2 = __builtin_bit_cast(frag8, fw);                                   \
      w0 = pk2h(sB[8], sB[9]);   w1 = pk2h(sB[10], sB[11]);                  \
      w2 = pk2h(sB[12], sB[13]); w3 = pk2h(sB[14], sB[15]);                  \
      pl32swap(w0, w2); pl32swap(w1, w3);                                    \
      fw[0] = w0; fw[1] = w1; fw[2] = w2; fw[3] = w3;                        \
      pf3 = __builtin_bit_cast(frag8, fw);                                   \
    }                                                                        \
    /* PV: O^T += Vt-slice x P-slice over 4 k16-slices */                    \
    __builtin_amdgcn_s_setprio(1);                                           \
    {                                                                        \
      frag8 va, vb;                                                          \
      va = ld_frag(VbS + off2[0][0]); o0 = mfma32(va, pf0, o0);              \
      vb = ld_frag(VbS + off2[1][0]); o1 = mfma32(vb, pf0, o1);              \
      va = ld_frag(VbS + off2[0][1]); o0 = mfma32(va, pf1, o0);              \
      vb = ld_frag(VbS + off2[1][1]); o1 = mfma32(vb, pf1, o1);              \
      va = ld_frag(VbS + off2[0][2]); o0 = mfma32(va, pf2, o0);              \
      vb = ld_frag(VbS + off2[1][2]); o1 = mfma32(vb, pf2, o1);              \
      va = ld_frag(VbS + off2[0][3]); o0 = mfma32(va, pf3, o0);              \
      vb = ld_frag(VbS + off2[1][3]); o1 = mfma32(vb, pf3, o1);              \
    }                                                                        \
    __builtin_amdgcn_s_setprio(0);                                           \
  }

  for (int it = 0; it < 7; ++it) {   // kt 0..27
    ATTN_TILE(0, 1)
    ATTN_TILE(1, 1)
    ATTN_TILE(2, 1)
    ATTN_TILE(3, 1)
  }
  ATTN_TILE(0, 1)   // kt 28 (stages tile 30)
  ATTN_TILE(1, 1)   // kt 29 (stages tile 31)
  ATTN_TILE(2, 2)   // kt 30 (vm4: tile 30 complete)
  ATTN_TILE(3, 0)   // kt 31 (vm0)
#undef ATTN_TILE

  // epilogue: O^T -> Ow[B,S,D] fp16. Lane q = l31;
  // d = h*64 + dt*32 + rg*8 + hi*4 + {0..3} -> one b64 store per (dt,rg).
  {
    const float inv = 1.0f / l_r;
    short* dst = Ow + ((size_t)b * S_ + q0 + l31) * D_ + h * HD_ + hi * 4;
#pragma unroll
    for (int rg = 0; rg < 4; ++rg) {
      i32x2 w;
      w[0] = pk2h(o0[rg * 4 + 0] * inv, o0[rg * 4 + 1] * inv);
      w[1] = pk2h(o0[rg * 4 + 2] * inv, o0[rg * 4 + 3] * inv);
      *(i32x2*)(dst + rg * 8) = w;
      i32x2 w2;
      w2[0] = pk2h(o1[rg * 4 + 0] * inv, o1[rg * 4 + 1] * inv);
      w2[1] = pk2h(o1[rg * 4 + 2] * inv, o1[rg * 4 + 3] * inv);
      *(i32x2*)(dst + 32 + rg * 8) = w2;
    }
  }
}

// ---------------------------------------------------------------------------
extern "C" void kernel_launch(void* const* d_in, const int* in_sizes, int n_in,
                              void* d_out, int out_size, void* d_ws, size_t ws_size,
                              hipStream_t stream) {
  const float* q  = (const float*)d_in[0];
  const float* k  = (const float*)d_in[1];
  const float* v  = (const float*)d_in[2];
  const float* Wq = (const float*)d_in[3];
  const float* bq = (const float*)d_in[4];
  const float* Wk = (const float*)d_in[5];
  const float* bk = (const float*)d_in[6];
  const float* Wv = (const float*)d_in[7];
  const float* bv = (const float*)d_in[8];
  const float* Wo = (const float*)d_in[9];
  const float* bo = (const float*)d_in[10];

  const size_t NTOK = (size_t)B_ * S_ * D_;   // 4,194,304
  const size_t NW   = (size_t)D_ * D_;        // 1,048,576
  short* p = (short*)d_ws;
  short* wq = p; p += NW;    short* wk = p; p += NW;
  short* wv = p; p += NW;    short* wo = p; p += NW;
  short* Qf = p; p += NTOK;  short* Kf = p; p += NTOK;
  short* Vt = p; p += NTOK;  short* Ow = p; p += NTOK;

  dim3 blk(256);

  conv_w<<<2048, blk, 0, stream>>>(Wq, Wk, Wv, Wo, wq, wk, wv, wo);

  const float QS = 11.541560327111707f;  // 8 * log2(e): exp2-domain softmax
  gemm_qkv<<<768, blk, 0, stream>>>(q, k, v, wq, wk, wv, bq, bk, bv,
                                    Qf, Kf, Vt, QS);

  attn<<<512, dim3(256), 0, stream>>>(Qf, Kf, Vt, Ow);

  gemm_out<<<512, blk, 0, stream>>>(Ow, wo, bo, (float*)d_out);
}

// Round 9
// 219.975 us; speedup vs baseline: 1.0632x; 1.0632x over previous
//
#include <hip/hip_runtime.h>
#include <type_traits>
#include <utility>

#define B_ 2
#define S_ 2048
#define D_ 1024
#define H_ 16
#define HD_ 64
#define KDIM 1024

typedef __attribute__((ext_vector_type(8))) short    s16x8;
typedef __attribute__((ext_vector_type(8))) _Float16 h16x8;
typedef __attribute__((ext_vector_type(4))) float    f32x4;
typedef __attribute__((ext_vector_type(16))) float   f32x16;
typedef __attribute__((ext_vector_type(4))) int      i32x4;
typedef __attribute__((ext_vector_type(2))) int      i32x2;

// --- MFMA operand-type hedge (fp16) ---
template <typename T, typename = void> struct mfma_takes : std::false_type {};
template <typename T>
struct mfma_takes<T, std::void_t<decltype(__builtin_amdgcn_mfma_f32_16x16x32_f16(
    std::declval<T>(), std::declval<T>(), std::declval<f32x4>(), 0, 0, 0))>>
    : std::true_type {};
using frag8 = std::conditional_t<mfma_takes<h16x8>::value, h16x8, s16x8>;

__device__ __forceinline__ f32x4 mfma_f16(frag8 a, frag8 b, f32x4 c) {
  return __builtin_amdgcn_mfma_f32_16x16x32_f16(a, b, c, 0, 0, 0);
}
__device__ __forceinline__ f32x16 mfma32(frag8 a, frag8 b, f32x16 c) {
  return __builtin_amdgcn_mfma_f32_32x32x16_f16(a, b, c, 0, 0, 0);
}

__device__ __forceinline__ short f2h(float f) {  // RTNE f32 -> fp16 bits
  _Float16 h = (_Float16)f;
  short s; __builtin_memcpy(&s, &h, 2);
  return s;
}
__device__ __forceinline__ int pk2h(float a, float b) {  // v_cvt_pkrtz 2xfp16
  auto p = __builtin_amdgcn_cvt_pkrtz(a, b);   // __fp16 ext_vector(2)
  int r; __builtin_memcpy(&r, &p, 4); return r;
}
__device__ __forceinline__ frag8 ld_frag(const short* p) {
  return __builtin_bit_cast(frag8, *(const i32x4*)p);
}
__device__ __forceinline__ float fast_exp2(float x) {
  return __builtin_amdgcn_exp2f(x);
}
// v_permlane32_swap_b32: vdst[32:63] <-> src0[0:31] (both operands modified)
__device__ __forceinline__ void pl32swap(int& a, int& b) {
  asm volatile("v_permlane32_swap_b32 %0, %1" : "+v"(a), "+v"(b));
}
// fp32x8 -> fp16x8 convert + one b128 LDS store
__device__ __forceinline__ void cvt_store8(f32x4 va, f32x4 vb, short* dst) {
  short pk[8] = { f2h(va[0]), f2h(va[1]), f2h(va[2]), f2h(va[3]),
                  f2h(vb[0]), f2h(vb[1]), f2h(vb[2]), f2h(vb[3]) };
  i32x4 w; __builtin_memcpy(&w, pk, 16);
  *(i32x4*)dst = w;
}

typedef __attribute__((address_space(1))) const void gvoid;
typedef __attribute__((address_space(3))) void lvoid;
__device__ __forceinline__ void async_copy16(const void* g, void* l) {
  __builtin_amdgcn_global_load_lds((gvoid*)g, (lvoid*)l, 16, 0, 0);
}

#define RAW_BARRIER() asm volatile("s_barrier" ::: "memory")
#define WAITCNT_VM(n) asm volatile("s_waitcnt vmcnt(" #n ")" ::: "memory")

// ---------------------------------------------------------------------------
// Weights-only fp32 -> fp16 convert (activations fused into gemm_qkv).
// ---------------------------------------------------------------------------
__global__ __launch_bounds__(256)
void conv_w(const float* __restrict__ Wq, const float* __restrict__ Wk,
            const float* __restrict__ Wv, const float* __restrict__ Wo,
            short* __restrict__ wq, short* __restrict__ wk,
            short* __restrict__ wv, short* __restrict__ wo) {
  const int blk = blockIdx.x;
  const float* src; short* dst; int base;
  if (blk < 512)        { src = Wq; dst = wq; base = blk; }
  else if (blk < 1024)  { src = Wk; dst = wk; base = blk - 512; }
  else if (blk < 1536)  { src = Wv; dst = wv; base = blk - 1024; }
  else                  { src = Wo; dst = wo; base = blk - 1536; }
  const int i = base * 2048 + threadIdx.x * 8;
  float4 a0 = *(const float4*)(src + i);
  float4 a1 = *(const float4*)(src + i + 4);
  short h[8] = { f2h(a0.x), f2h(a0.y), f2h(a0.z), f2h(a0.w),
                 f2h(a1.x), f2h(a1.y), f2h(a1.z), f2h(a1.w) };
  i32x4 ph; __builtin_memcpy(&ph, h, 16);
  *(i32x4*)(dst + i) = ph;
}

// ---------------------------------------------------------------------------
// QKV projection GEMM with fused fp32->fp16 A conversion. R9: A reg-staging
// deepened to PREFETCH DISTANCE 2 (two alternating compile-time register
// sets; R8's distance-1 was latency-bound: MfmaUtil 14.5%, VALU 11%, HBM
// 14.5%, nothing saturated at 66us). FIFO-verified vmcnt protocol, per-iter
// issue order [writeA(kk+32), 4x loadA(kk+96), 2x stageB(kk+64)]:
// steady queue = [A(kk+32)4, B(kk)2, A(kk+64)4, B(kk+32)2] -> vm(6) drains
// exactly A(kk+32)+B(kk). Tails: vm(6) @928, vm(2) @960, vm(0) @992.
// Ring of 3 LDS slots; A-slot write is >=3 barriers after its last reader.
// Tile 128x128, BK=32. A-GROUPED XCD DECODE. Epilogue b128 stores.
// ---------------------------------------------------------------------------
__global__ __launch_bounds__(256, 3)
void gemm_qkv(const float* __restrict__ Aq, const float* __restrict__ Ak,
              const float* __restrict__ Av, const short* __restrict__ wq,
              const short* __restrict__ wk, const short* __restrict__ wv,
              const float* __restrict__ bq, const float* __restrict__ bk,
              const float* __restrict__ bv, short* __restrict__ Qf,
              short* __restrict__ Kf, short* __restrict__ Vt, float QS) {
  __shared__ short As[3 * 4096];
  __shared__ short Bs[3 * 4096];

  const int blk = blockIdx.x;
  const int xcd = blk & 7, i = blk >> 3;      // i in [0,96)
  const int p = (i >> 3) * 8 + xcd;           // A-tile id, p ≡ xcd (mod 8)
  const int bn = i & 7;
  const int z = p >> 5, bm = p & 31;
  const float* Af = z == 0 ? Aq : z == 1 ? Ak : Av;
  const short* Wp = z == 0 ? wq : z == 1 ? wk : wv;
  const float* bias = z == 0 ? bq : z == 1 ? bk : bv;
  short* Out = z == 0 ? Qf : z == 1 ? Kf : Vt;
  const float scale = z == 0 ? QS : 1.0f;
  const int omode = z == 2 ? 2 : 1;

  const int t = threadIdx.x, wave = t >> 6, lane = t & 63;
  const int laneN = lane & 15, quad = lane >> 4;
  const int wm = wave & 1, wn = wave >> 1;

  f32x4 acc[4][4];
#pragma unroll
  for (int i2 = 0; i2 < 4; ++i2)
#pragma unroll
    for (int j = 0; j < 4; ++j)
#pragma unroll
      for (int r = 0; r < 4; ++r) acc[i2][j][r] = 0.f;

  // ---- A reg-stage descriptors: 2 chunks/thread, same swizzled layout ----
  const int ch0 = t, ch1 = 256 + t;
  const int ar0 = ch0 >> 2, ag0 = (ch0 & 3) ^ ((ar0 >> 1) & 3);
  const int ar1 = ch1 >> 2, ag1 = (ch1 & 3) ^ ((ar1 >> 1) & 3);
  const float* ap0 = Af + (size_t)(bm * 128 + ar0) * KDIM + ag0 * 8;
  const float* ap1 = Af + (size_t)(bm * 128 + ar1) * KDIM + ag1 * 8;

  // Two pending A register sets (compile-time selected; rule #20)
  f32x4 s0_0, s0_1, s0_2, s0_3;
  f32x4 s1_0, s1_1, s1_2, s1_3;

#define LOADA(S, KK)                                                         \
  do {                                                                       \
    if (S) {                                                                 \
      s1_0 = *(const f32x4*)(ap0 + (KK));                                    \
      s1_1 = *(const f32x4*)(ap0 + (KK) + 4);                                \
      s1_2 = *(const f32x4*)(ap1 + (KK));                                    \
      s1_3 = *(const f32x4*)(ap1 + (KK) + 4);                                \
    } else {                                                                 \
      s0_0 = *(const f32x4*)(ap0 + (KK));                                    \
      s0_1 = *(const f32x4*)(ap0 + (KK) + 4);                                \
      s0_2 = *(const f32x4*)(ap1 + (KK));                                    \
      s0_3 = *(const f32x4*)(ap1 + (KK) + 4);                                \
    }                                                                        \
  } while (0)

#define WRITEA(S, SLOT)                                                      \
  do {                                                                       \
    short* dA = As + (SLOT) * 4096;                                          \
    if (S) {                                                                 \
      cvt_store8(s1_0, s1_1, dA + ch0 * 8);                                  \
      cvt_store8(s1_2, s1_3, dA + ch1 * 8);                                  \
    } else {                                                                 \
      cvt_store8(s0_0, s0_1, dA + ch0 * 8);                                  \
      cvt_store8(s0_2, s0_3, dA + ch1 * 8);                                  \
    }                                                                        \
  } while (0)

  auto stageB = [&](int slot, int kk) {   // 2 asyncs/thread
#pragma unroll
    for (int j = 0; j < 2; ++j) {
      const int chunk = j * 256 + t;
      const int row = chunk >> 2;
      const int gg = (chunk & 3) ^ ((row >> 1) & 3);
      async_copy16(Wp + (size_t)(bn * 128 + row) * KDIM + kk + gg * 8,
                   Bs + slot * 4096 + chunk * 8);
    }
  };

  auto compute = [&](int cb) {
    frag8 aF[4], bF[4];
#pragma unroll
    for (int mi = 0; mi < 4; ++mi) {
      const int row = wm * 64 + mi * 16 + laneN;
      aF[mi] = ld_frag(As + cb * 4096 + row * 32 +
                       ((quad ^ ((row >> 1) & 3)) * 8));
    }
#pragma unroll
    for (int ni = 0; ni < 4; ++ni) {
      const int row = wn * 64 + ni * 16 + laneN;
      bF[ni] = ld_frag(Bs + cb * 4096 + row * 32 +
                       ((quad ^ ((row >> 1) & 3)) * 8));
    }
#pragma unroll
    for (int mi = 0; mi < 4; ++mi)
#pragma unroll
      for (int ni = 0; ni < 4; ++ni)
        acc[mi][ni] = mfma_f16(aF[mi], bF[ni], acc[mi][ni]);
  };

  // prologue: A(0)->set0, A(32)->set1, B(0),B(32) async; A(0)->slot0;
  // A(64)->set0.  Queue after: [A(32)4, B(0)2, B(32)2, A(64)4] = 12.
  LOADA(0, 0);
  LOADA(1, 32);
  stageB(0, 0);
  stageB(1, 32);
  WAITCNT_VM(8);        // drain A(0)
  WRITEA(0, 0);
  LOADA(0, 64);

  int buf = 0, kk = 0;

// One full iteration. S = compile-time reg-set for writeA(A(kk+32)) and
// loadA(kk+96). kk/32 even -> S=1, odd -> S=0.
#define QKV_ITER(S)                                                          \
  {                                                                          \
    WAITCNT_VM(6);      /* drain A(kk+32) + B(kk) */                         \
    int ns = buf + 1; if (ns >= 3) ns -= 3;                                  \
    WRITEA(S, ns);                                                           \
    LOADA(S, kk + 96);                                                       \
    int nb = ns + 1; if (nb >= 3) nb -= 3;                                   \
    stageB(nb, kk + 64);                                                     \
    RAW_BARRIER();                                                           \
    compute(buf);                                                            \
    RAW_BARRIER();                                                           \
    buf = ns; kk += 32;                                                      \
  }

  for (int it = 0; it < 14; ++it) {   // kk = 0..864 (28 iters)
    QKV_ITER(1)
    QKV_ITER(0)
  }
  QKV_ITER(1)                         // kk = 896: loadA(992), stageB(960)
#undef QKV_ITER

  // kk = 928: writeA(A(960), set0), stageB(992); no more A loads
  {
    WAITCNT_VM(6);      // drain A(960) + B(928)
    int ns = buf + 1; if (ns >= 3) ns -= 3;      // slot(960)
    WRITEA(0, ns);
    int nb = ns + 1; if (nb >= 3) nb -= 3;       // slot(992)
    stageB(nb, 992);
    RAW_BARRIER();
    compute(buf);
    RAW_BARRIER();
    buf = ns;
  }
  // kk = 960: writeA(A(992), set1)
  {
    WAITCNT_VM(2);      // drain A(992) + B(960); leave B(992)
    int ns = buf + 1; if (ns >= 3) ns -= 3;      // slot(992)
    WRITEA(1, ns);
    RAW_BARRIER();
    compute(buf);
    RAW_BARRIER();
    buf = ns;
  }
  // kk = 992
  {
    WAITCNT_VM(0);
    RAW_BARRIER();
    compute(buf);
    RAW_BARRIER();
  }
#undef LOADA
#undef WRITEA

  // ---- Epilogue via per-wave LDS restage (As free past final barrier).
  short* scr = As + wave * 1152;
  const int h = bn * 2 + wn;
  if (omode == 2) {
    const int bidx = bm >> 4;
    const int sbase = (bm * 128 + wm * 64) & 2047;
#pragma unroll
    for (int ni = 0; ni < 4; ++ni) {
      const float bb = bias[bn * 128 + wn * 64 + ni * 16 + laneN];
#pragma unroll
      for (int mi = 0; mi < 4; ++mi) {
        short pk[4];
#pragma unroll
        for (int r = 0; r < 4; ++r) pk[r] = f2h(acc[mi][ni][r] + bb);
        i32x2 w; __builtin_memcpy(&w, pk, 8);
        *(i32x2*)(scr + laneN * 72 + mi * 16 + quad * 4) = w;
      }
#pragma unroll
      for (int j = 0; j < 2; ++j) {
        const int ff = lane * 2 + j, hdr = ff >> 3, ch = ff & 7;
        i32x4 v = *(const i32x4*)(scr + hdr * 72 + ch * 8);
        *(i32x4*)(Vt + (((size_t)(bidx * H_ + h)) * HD_ + ni * 16 + hdr) * S_ +
                  sbase + ch * 8) = v;
      }
    }
  } else {
#pragma unroll
    for (int mi = 0; mi < 4; ++mi) {
#pragma unroll
      for (int ni = 0; ni < 4; ++ni) {
        const float bb = bias[bn * 128 + wn * 64 + ni * 16 + laneN];
#pragma unroll
        for (int r = 0; r < 4; ++r)
          scr[(quad * 4 + r) * 72 + ni * 16 + laneN] =
              f2h((acc[mi][ni][r] + bb) * scale);
      }
#pragma unroll
      for (int j = 0; j < 2; ++j) {
        const int ff = lane * 2 + j, row = ff >> 3, ch = ff & 7;
        const int rowg = bm * 128 + wm * 64 + mi * 16 + row;
        const int bidx = rowg >> 11, s = rowg & 2047;
        i32x4 v = *(const i32x4*)(scr + row * 72 + ch * 8);
        *(i32x4*)(Out + (((size_t)(bidx * H_ + h)) * S_ + s) * HD_ + ch * 8) = v;
      }
    }
  }
}

// ---------------------------------------------------------------------------
// O projection: fp16 A x fp16 Wo -> fp32. Tile 128(M)x64(N). BK=64
// double-buffered (48KB LDS), counted vm(6), 16 MFMA per barrier-pair.
// ---------------------------------------------------------------------------
__global__ __launch_bounds__(256, 3)
void gemm_out(const short* __restrict__ Ap, const short* __restrict__ Wp,
              const float* __restrict__ bias, float* __restrict__ Out) {
  __shared__ short As[2 * 8192];   // 2 x 128r x 64k
  __shared__ short Bs[2 * 4096];   // 2 x  64r x 64k
  const int blk = blockIdx.x;
  const int xcd = blk & 7, i = blk >> 3;      // i in [0,64)
  const int bm = (i >> 4) * 8 + xcd;          // bm ≡ xcd (mod 8)
  const int bn = i & 15;

  const int t = threadIdx.x, wave = t >> 6, lane = t & 63;
  const int laneN = lane & 15, quad = lane >> 4;
  const int wm = wave & 1, wn = wave >> 1;

  f32x4 acc[4][2];
#pragma unroll
  for (int i2 = 0; i2 < 4; ++i2)
#pragma unroll
    for (int j = 0; j < 2; ++j)
#pragma unroll
      for (int r = 0; r < 4; ++r) acc[i2][j][r] = 0.f;

  auto stage = [&](int buf, int kk) {   // 6 asyncs/thread per call
#pragma unroll
    for (int j = 0; j < 4; ++j) {       // A: 1024 chunks
      const int c = j * 256 + t;
      const int row = c >> 3, g = (c & 7) ^ (row & 7);
      async_copy16(Ap + (size_t)(bm * 128 + row) * KDIM + kk + g * 8,
                   As + buf * 8192 + c * 8);
    }
#pragma unroll
    for (int j = 0; j < 2; ++j) {       // B: 512 chunks
      const int c = j * 256 + t;
      const int row = c >> 3, g = (c & 7) ^ (row & 7);
      async_copy16(Wp + (size_t)(bn * 64 + row) * KDIM + kk + g * 8,
                   Bs + buf * 4096 + c * 8);
    }
  };

  // frag offsets: row*64 + ((quad+4*ks) ^ (row&7))*8
  int offA[4][2], offB[2][2];
#pragma unroll
  for (int mi = 0; mi < 4; ++mi) {
    const int row = wm * 64 + mi * 16 + laneN;
#pragma unroll
    for (int ks = 0; ks < 2; ++ks)
      offA[mi][ks] = row * 64 + (((quad + 4 * ks) ^ (row & 7)) * 8);
  }
#pragma unroll
  for (int ni = 0; ni < 2; ++ni) {
    const int row = wn * 32 + ni * 16 + laneN;
#pragma unroll
    for (int ks = 0; ks < 2; ++ks)
      offB[ni][ks] = row * 64 + (((quad + 4 * ks) ^ (row & 7)) * 8);
  }

  stage(0, 0);
  int buf = 0;
  for (int kk = 0; kk < KDIM; kk += 64) {
    if (kk + 64 < KDIM) {
      stage(buf ^ 1, kk + 64);
      WAITCNT_VM(6);        // current tile's 6 complete; next's in flight
    } else {
      WAITCNT_VM(0);
    }
    RAW_BARRIER();

    frag8 aF[4][2], bF[2][2];
#pragma unroll
    for (int mi = 0; mi < 4; ++mi) {
      aF[mi][0] = ld_frag(As + buf * 8192 + offA[mi][0]);
      aF[mi][1] = ld_frag(As + buf * 8192 + offA[mi][1]);
    }
#pragma unroll
    for (int ni = 0; ni < 2; ++ni) {
      bF[ni][0] = ld_frag(Bs + buf * 4096 + offB[ni][0]);
      bF[ni][1] = ld_frag(Bs + buf * 4096 + offB[ni][1]);
    }
#pragma unroll
    for (int mi = 0; mi < 4; ++mi)
#pragma unroll
      for (int ni = 0; ni < 2; ++ni) {
        acc[mi][ni] = mfma_f16(aF[mi][0], bF[ni][0], acc[mi][ni]);
        acc[mi][ni] = mfma_f16(aF[mi][1], bF[ni][1], acc[mi][ni]);
      }
    RAW_BARRIER();
    buf ^= 1;
  }

  // ---- Epilogue via per-wave LDS restage: [16 rows][36 f32] strip.
  float* scr = (float*)As + wave * 576;
#pragma unroll
  for (int mi = 0; mi < 4; ++mi) {
#pragma unroll
    for (int ni = 0; ni < 2; ++ni) {
      const float bb = bias[bn * 64 + wn * 32 + ni * 16 + laneN];
#pragma unroll
      for (int r = 0; r < 4; ++r)
        scr[(quad * 4 + r) * 36 + ni * 16 + laneN] = acc[mi][ni][r] + bb;
    }
#pragma unroll
    for (int j = 0; j < 2; ++j) {
      const int ff = lane * 2 + j, row = ff >> 3, ch = ff & 7;
      const int rowg = bm * 128 + wm * 64 + mi * 16 + row;
      f32x4 v = *(const f32x4*)(scr + row * 36 + ch * 4);
      *(f32x4*)(Out + (size_t)rowg * 1024 + bn * 64 + wn * 32 + ch * 4) = v;
    }
  }
}

// ---------------------------------------------------------------------------
// Flash attention, fp16. R7 structure (kept, 59.7us): 32 q/wave via
// 32x32x16 MFMA, in-register P (cvt_pkrtz + permlane32_swap), 512 blocks x
// 256 threads, ring-4 K/V 64KB, one barrier/kt, counted vm(8).
// ---------------------------------------------------------------------------
__global__ __launch_bounds__(256, 2)
void attn(const short* __restrict__ Qf, const short* __restrict__ Kf,
          const short* __restrict__ Vt_, short* __restrict__ Ow) {
  __shared__ short Ks[4 * 4096];     // 4 x 64k x 64d
  __shared__ short Vts[4 * 4096];    // 4 x 64d x 64k

  // XCD-locality: 512 blocks, 8 groups x 4 (h,b) pairs x 16 q-tiles of 128
  const int blk = blockIdx.x;
  const int xcd = blk & 7, local = blk >> 3;
  const int pair = xcd * 4 + (local >> 4);
  const int h = pair & 15, b = pair >> 4, qt = local & 15;
  const size_t head = ((size_t)b * H_ + h) * (size_t)S_ * HD_;

  const int t = threadIdx.x;
  const int wave = t >> 6, lane = t & 63;
  const int l31 = lane & 31, hi = lane >> 5;

  const int q0 = qt * 128 + wave * 32;

  // Q frags (B-operand of 32x32x16): col q = l31, contraction d = ds*16+hi*8
  frag8 qf[4];
  {
    const short* qp = Qf + head + (size_t)(q0 + l31) * HD_ + hi * 8;
#pragma unroll
    for (int ds = 0; ds < 4; ++ds) qf[ds] = ld_frag(qp + ds * 16);
  }

  // O^T accumulators: dt in {0,1}; C/D: col q = l31,
  // row d = dt*32 + (r&3) + 8*(r>>2) + 4*hi
  f32x16 o0, o1;
#pragma unroll
  for (int r = 0; r < 16; ++r) { o0[r] = 0.f; o1[r] = 0.f; }
  float m_r = -1e30f, l_r = 0.f;

  // ---- staging: 2 K-chunks + 2 V-chunks per thread (8KB tiles) ----
  const int c0 = t, c1 = 256 + t;
  const int r0 = c0 >> 3, gg0 = (c0 & 7) ^ (r0 & 7);
  const int r1 = c1 >> 3, gg1 = (c1 & 7) ^ (r1 & 7);
  const short* kp0 = Kf + head + (size_t)r0 * HD_ + gg0 * 8;  // += 4096/kt
  const short* kp1 = Kf + head + (size_t)r1 * HD_ + gg1 * 8;
  const short* vp0 = Vt_ + head + (size_t)r0 * S_ + gg0 * 8;  // += 64/kt
  const short* vp1 = Vt_ + head + (size_t)r1 * S_ + gg1 * 8;
  const int d0 = c0 * 8, d1 = c1 * 8;

  // frag offsets (same table serves K rows k and V rows d):
  // row = hf*32 + l31, granule = (j*2 + hi) ^ (row&7)
  int off2[2][4];
#pragma unroll
  for (int hf = 0; hf < 2; ++hf) {
    const int row = hf * 32 + l31;
#pragma unroll
    for (int j = 0; j < 4; ++j)
      off2[hf][j] = row * 64 + (((j * 2 + hi) ^ (row & 7)) * 8);
  }

  // prologue: stage tiles 0,1 (prefetch distance 2)
  async_copy16(kp0, Ks + d0);  async_copy16(kp1, Ks + d1);
  async_copy16(vp0, Vts + d0); async_copy16(vp1, Vts + d1);
  kp0 += 4096; kp1 += 4096; vp0 += 64; vp1 += 64;
  async_copy16(kp0, Ks + 4096 + d0);  async_copy16(kp1, Ks + 4096 + d1);
  async_copy16(vp0, Vts + 4096 + d0); async_copy16(vp1, Vts + 4096 + d1);
  kp0 += 4096; kp1 += 4096; vp0 += 64; vp1 += 64;

// One kt step. B0 = kt&3 compile-time; stage -> (B0+2)&3.
// STG: 1 = stage + vm(8); 2 = vm(4); 0 = vm(0).
#define ATTN_TILE(B0, STG)                                                   \
  {                                                                          \
    if (STG == 1) {                                                          \
      const int nb = ((B0) + 2) & 3;                                         \
      async_copy16(kp0, Ks + nb * 4096 + d0);                                \
      async_copy16(kp1, Ks + nb * 4096 + d1);                                \
      async_copy16(vp0, Vts + nb * 4096 + d0);                               \
      async_copy16(vp1, Vts + nb * 4096 + d1);                               \
      kp0 += 4096; kp1 += 4096; vp0 += 64; vp1 += 64;                        \
      WAITCNT_VM(8);                                                         \
    } else if (STG == 2) {                                                   \
      WAITCNT_VM(4);                                                         \
    } else {                                                                 \
      WAITCNT_VM(0);                                                         \
    }                                                                        \
    RAW_BARRIER();                                                           \
    const short* KbS = Ks + (B0) * 4096;                                     \
    const short* VbS = Vts + (B0) * 4096;                                    \
    /* S^T = K.Q^T: kh halves -> sA (k 0..31), sB (k 32..63) */              \
    f32x16 sA, sB;                                                           \
    _Pragma("unroll")                                                        \
    for (int r = 0; r < 16; ++r) { sA[r] = 0.f; sB[r] = 0.f; }               \
    __builtin_amdgcn_s_setprio(1);                                           \
    _Pragma("unroll")                                                        \
    for (int ds = 0; ds < 4; ++ds) {                                         \
      frag8 ka = ld_frag(KbS + off2[0][ds]);                                 \
      frag8 kb = ld_frag(KbS + off2[1][ds]);                                 \
      sA = mfma32(ka, qf[ds], sA);                                           \
      sB = mfma32(kb, qf[ds], sB);                                           \
    }                                                                        \
    __builtin_amdgcn_s_setprio(0);                                           \
    /* online softmax: 31 in-lane + 1 shfl32; defer-max THR=8 */             \
    {                                                                        \
      float mA = sA[0], mB = sB[0];                                          \
      _Pragma("unroll")                                                      \
      for (int r = 1; r < 16; ++r) {                                         \
        mA = fmaxf(mA, sA[r]); mB = fmaxf(mB, sB[r]);                        \
      }                                                                      \
      float mx = fmaxf(mA, mB);                                              \
      mx = fmaxf(mx, __shfl_xor(mx, 32));                                    \
      if (__any(mx > m_r + 8.f)) {                                           \
        const float mn = fmaxf(m_r, mx);                                     \
        const float al = fast_exp2(m_r - mn);                                \
        m_r = mn; l_r *= al;                                                 \
        _Pragma("unroll")                                                    \
        for (int r = 0; r < 16; ++r) { o0[r] *= al; o1[r] *= al; }           \
      }                                                                      \
      float rs = 0.f;                                                        \
      _Pragma("unroll")                                                      \
      for (int r = 0; r < 16; ++r) {                                         \
        const float pa = fast_exp2(sA[r] - m_r);                             \
        const float pb = fast_exp2(sB[r] - m_r);                             \
        sA[r] = pa; sB[r] = pb; rs += pa + pb;                               \
      }                                                                      \
      rs += __shfl_xor(rs, 32);                                              \
      l_r += rs;                                                             \
    }                                                                        \
    /* P -> B-frags in registers: per k16-slice 4 cvt_pk + 2 permlane32 */   \
    frag8 pf0, pf1, pf2, pf3;                                                \
    {                                                                        \
      int w0, w1, w2, w3; i32x4 fw;                                          \
      w0 = pk2h(sA[0], sA[1]);   w1 = pk2h(sA[2], sA[3]);                    \
      w2 = pk2h(sA[4], sA[5]);   w3 = pk2h(sA[6], sA[7]);                    \
      pl32swap(w0, w2); pl32swap(w1, w3);                                    \
      fw[0] = w0; fw[1] = w1; fw[2] = w2; fw[3] = w3;                        \
      pf0 = __builtin_bit_cast(frag8, fw);                                   \
      w0 = pk2h(sA[8], sA[9]);   w1 = pk2h(sA[10], sA[11]);                  \
      w2 = pk2h(sA[12], sA[13]); w3 = pk2h(sA[14], sA[15]);                  \
      pl32swap(w0, w2); pl32swap(w1, w3);                                    \
      fw[0] = w0; fw[1] = w1; fw[2] = w2; fw[3] = w3;                        \
      pf1 = __builtin_bit_cast(frag8, fw);                                   \
      w0 = pk2h(sB[0], sB[1]);   w1 = pk2h(sB[2], sB[3]);                    \
      w2 = pk2h(sB[4], sB[5]);   w3 = pk2h(sB[6], sB[7]);                    \
      pl32swap(w0, w2); pl32swap(w1, w3);                                    \
      fw[0] = w0; fw[1] = w1; fw[2] = w2; fw[3] = w3;                        \
      pf2 = __builtin_bit_cast(frag8, fw);                                   \
      w0 = pk2h(sB[8], sB[9]);   w1 = pk2h(sB[10], sB[11]);                  \
      w2 = pk2h(sB[12], sB[13]); w3 = pk2h(sB[14], sB[15]);                  \
      pl32swap(w0, w2); pl32swap(w1, w3);                                    \
      fw[0] = w0; fw[1] = w1; fw[2] = w2; fw[3] = w3;                        \
      pf3 = __builtin_bit_cast(frag8, fw);                                   \
    }                                                                        \
    /* PV: O^T += Vt-slice x P-slice over 4 k16-slices */                    \
    __builtin_amdgcn_s_setprio(1);                                           \
    {                                                                        \
      frag8 va, vb;                                                          \
      va = ld_frag(VbS + off2[0][0]); o0 = mfma32(va, pf0, o0);              \
      vb = ld_frag(VbS + off2[1][0]); o1 = mfma32(vb, pf0, o1);              \
      va = ld_frag(VbS + off2[0][1]); o0 = mfma32(va, pf1, o0);              \
      vb = ld_frag(VbS + off2[1][1]); o1 = mfma32(vb, pf1, o1);              \
      va = ld_frag(VbS + off2[0][2]); o0 = mfma32(va, pf2, o0);              \
      vb = ld_frag(VbS + off2[1][2]); o1 = mfma32(vb, pf2, o1);              \
      va = ld_frag(VbS + off2[0][3]); o0 = mfma32(va, pf3, o0);              \
      vb = ld_frag(VbS + off2[1][3]); o1 = mfma32(vb, pf3, o1);              \
    }                                                                        \
    __builtin_amdgcn_s_setprio(0);                                           \
  }

  for (int it = 0; it < 7; ++it) {   // kt 0..27
    ATTN_TILE(0, 1)
    ATTN_TILE(1, 1)
    ATTN_TILE(2, 1)
    ATTN_TILE(3, 1)
  }
  ATTN_TILE(0, 1)   // kt 28 (stages tile 30)
  ATTN_TILE(1, 1)   // kt 29 (stages tile 31)
  ATTN_TILE(2, 2)   // kt 30 (vm4: tile 30 complete)
  ATTN_TILE(3, 0)   // kt 31 (vm0)
#undef ATTN_TILE

  // epilogue: O^T -> Ow[B,S,D] fp16. Lane q = l31;
  // d = h*64 + dt*32 + rg*8 + hi*4 + {0..3} -> one b64 store per (dt,rg).
  {
    const float inv = 1.0f / l_r;
    short* dst = Ow + ((size_t)b * S_ + q0 + l31) * D_ + h * HD_ + hi * 4;
#pragma unroll
    for (int rg = 0; rg < 4; ++rg) {
      i32x2 w;
      w[0] = pk2h(o0[rg * 4 + 0] * inv, o0[rg * 4 + 1] * inv);
      w[1] = pk2h(o0[rg * 4 + 2] * inv, o0[rg * 4 + 3] * inv);
      *(i32x2*)(dst + rg * 8) = w;
      i32x2 w2;
      w2[0] = pk2h(o1[rg * 4 + 0] * inv, o1[rg * 4 + 1] * inv);
      w2[1] = pk2h(o1[rg * 4 + 2] * inv, o1[rg * 4 + 3] * inv);
      *(i32x2*)(dst + 32 + rg * 8) = w2;
    }
  }
}

// ---------------------------------------------------------------------------
extern "C" void kernel_launch(void* const* d_in, const int* in_sizes, int n_in,
                              void* d_out, int out_size, void* d_ws, size_t ws_size,
                              hipStream_t stream) {
  const float* q  = (const float*)d_in[0];
  const float* k  = (const float*)d_in[1];
  const float* v  = (const float*)d_in[2];
  const float* Wq = (const float*)d_in[3];
  const float* bq = (const float*)d_in[4];
  const float* Wk = (const float*)d_in[5];
  const float* bk = (const float*)d_in[6];
  const float* Wv = (const float*)d_in[7];
  const float* bv = (const float*)d_in[8];
  const float* Wo = (const float*)d_in[9];
  const float* bo = (const float*)d_in[10];

  const size_t NTOK = (size_t)B_ * S_ * D_;   // 4,194,304
  const size_t NW   = (size_t)D_ * D_;        // 1,048,576
  short* p = (short*)d_ws;
  short* wq = p; p += NW;    short* wk = p; p += NW;
  short* wv = p; p += NW;    short* wo = p; p += NW;
  short* Qf = p; p += NTOK;  short* Kf = p; p += NTOK;
  short* Vt = p; p += NTOK;  short* Ow = p; p += NTOK;

  dim3 blk(256);

  conv_w<<<2048, blk, 0, stream>>>(Wq, Wk, Wv, Wo, wq, wk, wv, wo);

  const float QS = 11.541560327111707f;  // 8 * log2(e): exp2-domain softmax
  gemm_qkv<<<768, blk, 0, stream>>>(q, k, v, wq, wk, wv, bq, bk, bv,
                                    Qf, Kf, Vt, QS);

  attn<<<512, dim3(256), 0, stream>>>(Qf, Kf, Vt, Ow);

  gemm_out<<<512, blk, 0, stream>>>(Ow, wo, bo, (float*)d_out);
}